// Round 1
// baseline (1183.253 us; speedup 1.0000x reference)
//
#include <hip/hip_runtime.h>

#define NN 100000
#define NE 1600000
#define DD 128
#define NBLK_SCAN 98   // ceil(NN / 1024)

// ---------------- CSR build ----------------

__global__ __launch_bounds__(256) void hist_kernel(const int* __restrict__ row,
                                                   int* __restrict__ deg) {
    int i = blockIdx.x * blockDim.x + threadIdx.x;
    int stride = gridDim.x * blockDim.x;
    for (; i < NE; i += stride) atomicAdd(&deg[row[i]], 1);
}

// per-block (1024-elem chunk) sums
__global__ __launch_bounds__(256) void scanA_kernel(const int* __restrict__ deg,
                                                    int* __restrict__ bsum) {
    __shared__ int red[256];
    int base = blockIdx.x * 1024;
    int t = threadIdx.x;
    int s = 0;
#pragma unroll
    for (int k = 0; k < 4; ++k) {
        int i = base + t * 4 + k;
        if (i < NN) s += deg[i];
    }
    red[t] = s;
    __syncthreads();
    for (int off = 128; off > 0; off >>= 1) {
        if (t < off) red[t] += red[t + off];
        __syncthreads();
    }
    if (t == 0) bsum[blockIdx.x] = red[0];
}

// exclusive scan of the 98 block sums (tiny, serial)
__global__ void scanB_kernel(int* __restrict__ bsum, int nblk) {
    int acc = 0;
    for (int i = 0; i < nblk; ++i) { int v = bsum[i]; bsum[i] = acc; acc += v; }
}

// full exclusive offsets: offsets[0]=0, offsets[i+1]=inclusive sum through i
__global__ __launch_bounds__(256) void scanC_kernel(const int* __restrict__ deg,
                                                    const int* __restrict__ bsum,
                                                    int* __restrict__ offs) {
    __shared__ int tsum[256];
    int base = blockIdx.x * 1024;
    int t = threadIdx.x;
    int v[4];
    int s = 0;
#pragma unroll
    for (int k = 0; k < 4; ++k) {
        int i = base + t * 4 + k;
        v[k] = (i < NN) ? deg[i] : 0;
        s += v[k];
    }
    tsum[t] = s;
    __syncthreads();
    // Hillis-Steele inclusive scan over 256 thread sums
    for (int off = 1; off < 256; off <<= 1) {
        int add = (t >= off) ? tsum[t - off] : 0;
        __syncthreads();
        tsum[t] += add;
        __syncthreads();
    }
    int pre = bsum[blockIdx.x] + ((t > 0) ? tsum[t - 1] : 0);
#pragma unroll
    for (int k = 0; k < 4; ++k) {
        int i = base + t * 4 + k;
        pre += v[k];
        if (i < NN) offs[i + 1] = pre;
    }
    if (blockIdx.x == 0 && t == 0) offs[0] = 0;
}

__global__ __launch_bounds__(256) void scatter_kernel(const int* __restrict__ row,
                                                      const int* __restrict__ col,
                                                      const int* __restrict__ offs,
                                                      int* __restrict__ cursor,
                                                      int* __restrict__ csr_col) {
    int i = blockIdx.x * blockDim.x + threadIdx.x;
    int stride = gridDim.x * blockDim.x;
    for (; i < NE; i += stride) {
        int r = row[i];
        int p = offs[r] + atomicAdd(&cursor[r], 1);
        csr_col[p] = col[i];
    }
}

// ---------------- per-layer compute ----------------

// mean aggregation: 32 lanes per node, float4 per lane
__global__ __launch_bounds__(256) void aggregate_kernel(const float* __restrict__ h,
                                                        const int* __restrict__ offs,
                                                        const int* __restrict__ csr_col,
                                                        float* __restrict__ agg) {
    int node = blockIdx.x * (blockDim.x >> 5) + (threadIdx.x >> 5);
    if (node >= NN) return;
    int lane = threadIdx.x & 31;
    int s = offs[node], e = offs[node + 1];
    float4 acc = make_float4(0.f, 0.f, 0.f, 0.f);
    for (int p = s; p < e; ++p) {
        int c = csr_col[p];
        const float4 v = *reinterpret_cast<const float4*>(&h[(size_t)c * DD + lane * 4]);
        acc.x += v.x; acc.y += v.y; acc.z += v.z; acc.w += v.w;
    }
    float inv = (e > s) ? (1.0f / (float)(e - s)) : 0.0f;
    acc.x *= inv; acc.y *= inv; acc.z *= inv; acc.w *= inv;
    *reinterpret_cast<float4*>(&agg[(size_t)node * DD + lane * 4]) = acc;
}

// out[r][64*half + c] = relu( sum_k agg[r][k]*Wl[k][...] + h[r][k]*Wr[k][...] + b )
// one thread per row; half (blockIdx.y) keeps weight addresses wave-uniform.
__global__ __launch_bounds__(256) void gemm_kernel(const float* __restrict__ agg,
                                                   const float* __restrict__ h,
                                                   const float* __restrict__ Wl,
                                                   const float* __restrict__ Wr,
                                                   const float* __restrict__ bias,
                                                   float* __restrict__ out) {
    const int half = blockIdx.y;  // 0 or 1
    const int r = blockIdx.x * 256 + threadIdx.x;
    if (r >= NN) return;
    const float* wl = Wl + half * 64;
    const float* wr = Wr + half * 64;

    float acc[64];
#pragma unroll
    for (int c = 0; c < 64; ++c) acc[c] = 0.f;

    const float* arow = agg + (size_t)r * DD;
    const float* hrow = h + (size_t)r * DD;

    for (int k = 0; k < DD; k += 4) {
        float4 a4 = *reinterpret_cast<const float4*>(&arow[k]);
        float4 h4 = *reinterpret_cast<const float4*>(&hrow[k]);
#pragma unroll
        for (int kk = 0; kk < 4; ++kk) {
            float a = (&a4.x)[kk];
            float hh = (&h4.x)[kk];
            const float* wlrow = wl + (size_t)(k + kk) * DD;
            const float* wrrow = wr + (size_t)(k + kk) * DD;
#pragma unroll
            for (int c = 0; c < 64; ++c) {
                acc[c] += a * wlrow[c] + hh * wrrow[c];
            }
        }
    }

#pragma unroll
    for (int c = 0; c < 64; ++c) {
        float v = acc[c] + bias[half * 64 + c];
        out[(size_t)r * DD + half * 64 + c] = v > 0.f ? v : 0.f;
    }
}

extern "C" void kernel_launch(void* const* d_in, const int* in_sizes, int n_in,
                              void* d_out, int out_size, void* d_ws, size_t ws_size,
                              hipStream_t stream) {
    const float* x = (const float*)d_in[0];
    const int* ei = (const int*)d_in[1];
    const int* row = ei;        // dst
    const int* col = ei + NE;   // src
    const float* Wl[3] = {(const float*)d_in[2], (const float*)d_in[5], (const float*)d_in[8]};
    const float* Wr[3] = {(const float*)d_in[3], (const float*)d_in[6], (const float*)d_in[9]};
    const float* bb[3] = {(const float*)d_in[4], (const float*)d_in[7], (const float*)d_in[10]};
    float* out = (float*)d_out;

    // workspace carve-up (all 256B aligned)
    char* ws = (char*)d_ws;
    auto carve = [&](size_t bytes) {
        char* p = ws;
        ws += (bytes + 255) & ~(size_t)255;
        return p;
    };
    float* agg   = (float*)carve((size_t)NN * DD * sizeof(float)); // 51.2 MB
    int* deg     = (int*)carve((size_t)NN * sizeof(int));
    int* cursor  = (int*)carve((size_t)NN * sizeof(int));
    int* offs    = (int*)carve((size_t)(NN + 1) * sizeof(int));
    int* bsum    = (int*)carve(128 * sizeof(int));
    int* csr_col = (int*)carve((size_t)NE * sizeof(int));          // 6.4 MB

    hipMemsetAsync(deg, 0, (size_t)NN * sizeof(int), stream);
    hipMemsetAsync(cursor, 0, (size_t)NN * sizeof(int), stream);

    hist_kernel<<<2048, 256, 0, stream>>>(row, deg);
    scanA_kernel<<<NBLK_SCAN, 256, 0, stream>>>(deg, bsum);
    scanB_kernel<<<1, 1, 0, stream>>>(bsum, NBLK_SCAN);
    scanC_kernel<<<NBLK_SCAN, 256, 0, stream>>>(deg, bsum, offs);
    scatter_kernel<<<2048, 256, 0, stream>>>(row, col, offs, cursor, csr_col);

    const float* h = x;
    for (int l = 0; l < 3; ++l) {
        float* hout = out + (size_t)l * NN * DD;
        aggregate_kernel<<<(NN * 32) / 256, 256, 0, stream>>>(h, offs, csr_col, agg);
        dim3 g((NN + 255) / 256, 2);
        gemm_kernel<<<g, 256, 0, stream>>>(agg, h, Wl[l], Wr[l], bb[l], hout);
        h = hout;
    }
}

// Round 2
// 525.761 us; speedup vs baseline: 2.2506x; 2.2506x over previous
//
#include <hip/hip_runtime.h>

#define NN 100000
#define NE 1600000
#define DD 128
#define BM 128
#define NBLK_SCAN 98   // ceil(NN / 1024)

typedef __attribute__((ext_vector_type(4))) float f32x4;
typedef __attribute__((ext_vector_type(8))) short bf16x8;

__device__ inline unsigned short f2bf(float f) {
    unsigned int x = __builtin_bit_cast(unsigned int, f);
    unsigned int r = x + 0x7fffu + ((x >> 16) & 1u);
    return (unsigned short)(r >> 16);
}
__device__ inline float bf_lo(unsigned int u) { return __builtin_bit_cast(float, u << 16); }
__device__ inline float bf_hi(unsigned int u) { return __builtin_bit_cast(float, u & 0xffff0000u); }
__device__ inline unsigned int packbf(float a, float b) {
    return (unsigned int)f2bf(a) | ((unsigned int)f2bf(b) << 16);
}

__device__ inline void load_g2l_16(const void* gsrc, void* ldst) {
    __builtin_amdgcn_global_load_lds(
        (const __attribute__((address_space(1))) void*)(uintptr_t)gsrc,
        (__attribute__((address_space(3))) void*)(uintptr_t)ldst,
        16, 0, 0);
}

// ---------------- CSR build ----------------

__global__ __launch_bounds__(256) void hist_kernel(const int* __restrict__ row,
                                                   int* __restrict__ deg) {
    int i = blockIdx.x * blockDim.x + threadIdx.x;
    int stride = gridDim.x * blockDim.x;
    for (; i < NE; i += stride) atomicAdd(&deg[row[i]], 1);
}

__global__ __launch_bounds__(256) void scanA_kernel(const int* __restrict__ deg,
                                                    int* __restrict__ bsum) {
    __shared__ int red[256];
    int base = blockIdx.x * 1024;
    int t = threadIdx.x;
    int s = 0;
#pragma unroll
    for (int k = 0; k < 4; ++k) {
        int i = base + t * 4 + k;
        if (i < NN) s += deg[i];
    }
    red[t] = s;
    __syncthreads();
    for (int off = 128; off > 0; off >>= 1) {
        if (t < off) red[t] += red[t + off];
        __syncthreads();
    }
    if (t == 0) bsum[blockIdx.x] = red[0];
}

__global__ void scanB_kernel(int* __restrict__ bsum, int nblk) {
    int acc = 0;
    for (int i = 0; i < nblk; ++i) { int v = bsum[i]; bsum[i] = acc; acc += v; }
}

__global__ __launch_bounds__(256) void scanC_kernel(const int* __restrict__ deg,
                                                    const int* __restrict__ bsum,
                                                    int* __restrict__ offs) {
    __shared__ int tsum[256];
    int base = blockIdx.x * 1024;
    int t = threadIdx.x;
    int v[4];
    int s = 0;
#pragma unroll
    for (int k = 0; k < 4; ++k) {
        int i = base + t * 4 + k;
        v[k] = (i < NN) ? deg[i] : 0;
        s += v[k];
    }
    tsum[t] = s;
    __syncthreads();
    for (int off = 1; off < 256; off <<= 1) {
        int add = (t >= off) ? tsum[t - off] : 0;
        __syncthreads();
        tsum[t] += add;
        __syncthreads();
    }
    int pre = bsum[blockIdx.x] + ((t > 0) ? tsum[t - 1] : 0);
#pragma unroll
    for (int k = 0; k < 4; ++k) {
        int i = base + t * 4 + k;
        pre += v[k];
        if (i < NN) offs[i + 1] = pre;
    }
    if (blockIdx.x == 0 && t == 0) offs[0] = 0;
}

__global__ __launch_bounds__(256) void scatter_kernel(const int* __restrict__ row,
                                                      const int* __restrict__ col,
                                                      const int* __restrict__ offs,
                                                      int* __restrict__ cursor,
                                                      int* __restrict__ csr_col) {
    int i = blockIdx.x * blockDim.x + threadIdx.x;
    int stride = gridDim.x * blockDim.x;
    for (; i < NE; i += stride) {
        int r = row[i];
        int p = offs[r] + atomicAdd(&cursor[r], 1);
        csr_col[p] = col[i];
    }
}

// ---------------- dtype conversion ----------------

__global__ __launch_bounds__(256) void conv_x_kernel(const float* __restrict__ x,
                                                     unsigned short* __restrict__ xb) {
    int i = blockIdx.x * 256 + threadIdx.x;
    int stride = gridDim.x * 256;
    const int n4 = NN * DD / 4;
    for (; i < n4; i += stride) {
        float4 v = reinterpret_cast<const float4*>(x)[i];
        ushort4 o;
        o.x = f2bf(v.x); o.y = f2bf(v.y); o.z = f2bf(v.z); o.w = f2bf(v.w);
        reinterpret_cast<ushort4*>(xb)[i] = o;
    }
}

// WT[c][k] = bf16(W[k][c])   (transposed, bf16)
__global__ __launch_bounds__(256) void conv_w_kernel(const float* __restrict__ W,
                                                     unsigned short* __restrict__ WT) {
    int t = blockIdx.x * 256 + threadIdx.x;
    if (t >= DD * DD) return;
    int c = t >> 7, k = t & 127;
    WT[t] = f2bf(W[k * DD + c]);
}

// ---------------- per-layer compute ----------------

// mean aggregation over bf16 h: 16 lanes per node, 8 bf16 (16B) per lane
__global__ __launch_bounds__(256) void aggregate_bf16(const unsigned short* __restrict__ hb,
                                                      const int* __restrict__ offs,
                                                      const int* __restrict__ csr_col,
                                                      unsigned short* __restrict__ aggb) {
    int node = blockIdx.x * 16 + (threadIdx.x >> 4);
    if (node >= NN) return;
    int lane = threadIdx.x & 15;
    int s = offs[node], e = offs[node + 1];
    float a0 = 0, a1 = 0, a2 = 0, a3 = 0, a4 = 0, a5 = 0, a6 = 0, a7 = 0;
    for (int p = s; p < e; ++p) {
        int c = csr_col[p];
        uint4 v = *reinterpret_cast<const uint4*>(hb + (size_t)c * DD + lane * 8);
        a0 += bf_lo(v.x); a1 += bf_hi(v.x);
        a2 += bf_lo(v.y); a3 += bf_hi(v.y);
        a4 += bf_lo(v.z); a5 += bf_hi(v.z);
        a6 += bf_lo(v.w); a7 += bf_hi(v.w);
    }
    float inv = (e > s) ? (1.0f / (float)(e - s)) : 0.0f;
    uint4 o;
    o.x = packbf(a0 * inv, a1 * inv);
    o.y = packbf(a2 * inv, a3 * inv);
    o.z = packbf(a4 * inv, a5 * inv);
    o.w = packbf(a6 * inv, a7 * inv);
    *reinterpret_cast<uint4*>(aggb + (size_t)node * DD + lane * 8) = o;
}

// out[128-row tile] = relu(A @ Wl + H @ Wr + b), MFMA 16x16x32 bf16.
// LDS tiles staged via global_load_lds with pre-swizzled source; ds_read_b128
// with matching XOR swizzle (byte ^= (row&7)<<4) for conflict-free reads.
__global__ __launch_bounds__(256) void mfma_gemm_kernel(
    const unsigned short* __restrict__ Ab, const unsigned short* __restrict__ Hb,
    const unsigned short* __restrict__ WlT, const unsigned short* __restrict__ WrT,
    const float* __restrict__ bias, float* __restrict__ out,
    unsigned short* __restrict__ hbn) {
    __shared__ unsigned short Alds[BM * DD];
    __shared__ unsigned short Hlds[BM * DD];
    const int row0 = blockIdx.x * BM;
    const int tid = threadIdx.x;
    const int w = tid >> 6, l = tid & 63;

    const char* Asrc = (const char*)(Ab + (size_t)row0 * DD);
    const char* Hsrc = (const char*)(Hb + (size_t)row0 * DD);
    char* AldsB = (char*)Alds;
    char* HldsB = (char*)Hlds;

    // stage 32KB A + 32KB H; each wave fills an 8KB span of each
#pragma unroll
    for (int j = 0; j < 8; ++j) {
        int base = w * 8192 + j * 1024;
        int doff = base + l * 16;
        int soff = doff ^ (((doff >> 8) & 7) << 4);   // inverse swizzle on source
        if (row0 + (doff >> 8) < NN) {
            load_g2l_16(Asrc + soff, AldsB + base);
            load_g2l_16(Hsrc + soff, HldsB + base);
        }
    }
    __syncthreads();

    const int wr = w & 1, wc = w >> 1;
    const int lrow = l & 15, lg = l >> 4;

    f32x4 acc[4][4];
#pragma unroll
    for (int m = 0; m < 4; ++m)
#pragma unroll
        for (int n = 0; n < 4; ++n) acc[m][n] = (f32x4){0.f, 0.f, 0.f, 0.f};

    float bv[4];
#pragma unroll
    for (int n = 0; n < 4; ++n) bv[n] = bias[wc * 64 + n * 16 + lrow];

#pragma unroll
    for (int kb = 0; kb < 4; ++kb) {
        const int kbyte = kb * 64 + lg * 16;
        bf16x8 aA[4], aH[4];
#pragma unroll
        for (int m = 0; m < 4; ++m) {
            int rloc = wr * 64 + m * 16 + lrow;
            int off = (rloc << 8) + kbyte;
            off ^= (rloc & 7) << 4;
            aA[m] = *reinterpret_cast<const bf16x8*>(AldsB + off);
            aH[m] = *reinterpret_cast<const bf16x8*>(HldsB + off);
        }
        bf16x8 bL[4], bR[4];
#pragma unroll
        for (int n = 0; n < 4; ++n) {
            size_t woff = ((size_t)(wc * 64 + n * 16 + lrow) << 7) + kb * 32 + lg * 8;
            bL[n] = *reinterpret_cast<const bf16x8*>(WlT + woff);
            bR[n] = *reinterpret_cast<const bf16x8*>(WrT + woff);
        }
#pragma unroll
        for (int m = 0; m < 4; ++m)
#pragma unroll
            for (int n = 0; n < 4; ++n) {
                acc[m][n] = __builtin_amdgcn_mfma_f32_16x16x32_bf16(aA[m], bL[n], acc[m][n], 0, 0, 0);
                acc[m][n] = __builtin_amdgcn_mfma_f32_16x16x32_bf16(aH[m], bR[n], acc[m][n], 0, 0, 0);
            }
    }

#pragma unroll
    for (int m = 0; m < 4; ++m) {
        int grow_base = row0 + wr * 64 + m * 16 + lg * 4;
#pragma unroll
        for (int n = 0; n < 4; ++n) {
            int c = wc * 64 + n * 16 + lrow;
#pragma unroll
            for (int j = 0; j < 4; ++j) {
                int gr = grow_base + j;
                if (gr < NN) {
                    float v = acc[m][n][j] + bv[n];
                    v = fmaxf(v, 0.0f);
                    out[(size_t)gr * DD + c] = v;
                    if (hbn) hbn[(size_t)gr * DD + c] = f2bf(v);
                }
            }
        }
    }
}

extern "C" void kernel_launch(void* const* d_in, const int* in_sizes, int n_in,
                              void* d_out, int out_size, void* d_ws, size_t ws_size,
                              hipStream_t stream) {
    const float* x = (const float*)d_in[0];
    const int* ei = (const int*)d_in[1];
    const int* row = ei;        // dst
    const int* col = ei + NE;   // src
    const float* Wl[3] = {(const float*)d_in[2], (const float*)d_in[5], (const float*)d_in[8]};
    const float* Wr[3] = {(const float*)d_in[3], (const float*)d_in[6], (const float*)d_in[9]};
    const float* bb[3] = {(const float*)d_in[4], (const float*)d_in[7], (const float*)d_in[10]};
    float* out = (float*)d_out;

    char* ws = (char*)d_ws;
    auto carve = [&](size_t bytes) {
        char* p = ws;
        ws += (bytes + 255) & ~(size_t)255;
        return p;
    };
    unsigned short* buf0 = (unsigned short*)carve((size_t)NN * DD * 2);  // xb, reused as h2b
    unsigned short* buf1 = (unsigned short*)carve((size_t)NN * DD * 2);  // h1b
    unsigned short* aggb = (unsigned short*)carve((size_t)NN * DD * 2);
    unsigned short* wt[6];
    for (int i = 0; i < 6; ++i) wt[i] = (unsigned short*)carve((size_t)DD * DD * 2);
    int* deg     = (int*)carve((size_t)NN * sizeof(int));
    int* cursor  = (int*)carve((size_t)NN * sizeof(int));
    int* offs    = (int*)carve((size_t)(NN + 1) * sizeof(int));
    int* bsum    = (int*)carve(128 * sizeof(int));
    int* csr_col = (int*)carve((size_t)NE * sizeof(int));

    hipMemsetAsync(deg, 0, (size_t)NN * sizeof(int), stream);
    hipMemsetAsync(cursor, 0, (size_t)NN * sizeof(int), stream);

    conv_x_kernel<<<2048, 256, 0, stream>>>(x, buf0);
    for (int i = 0; i < 3; ++i) {
        conv_w_kernel<<<64, 256, 0, stream>>>(Wl[i], wt[2 * i]);
        conv_w_kernel<<<64, 256, 0, stream>>>(Wr[i], wt[2 * i + 1]);
    }

    hist_kernel<<<2048, 256, 0, stream>>>(row, deg);
    scanA_kernel<<<NBLK_SCAN, 256, 0, stream>>>(deg, bsum);
    scanB_kernel<<<1, 1, 0, stream>>>(bsum, NBLK_SCAN);
    scanC_kernel<<<NBLK_SCAN, 256, 0, stream>>>(deg, bsum, offs);
    scatter_kernel<<<2048, 256, 0, stream>>>(row, col, offs, cursor, csr_col);

    const int ngrid = (NN + BM - 1) / BM;   // 782
    const int agrid = (NN + 15) / 16;       // 6250

    unsigned short* hin = buf0;
    unsigned short* hout = buf1;
    for (int lyr = 0; lyr < 3; ++lyr) {
        float* o = out + (size_t)lyr * NN * DD;
        aggregate_bf16<<<agrid, 256, 0, stream>>>(hin, offs, csr_col, aggb);
        mfma_gemm_kernel<<<ngrid, 256, 0, stream>>>(
            aggb, hin, wt[2 * lyr], wt[2 * lyr + 1], bb[lyr], o,
            (lyr < 2) ? hout : (unsigned short*)nullptr);
        unsigned short* t = hin; hin = hout; hout = t;
    }
}

// Round 3
// 499.328 us; speedup vs baseline: 2.3697x; 1.0529x over previous
//
#include <hip/hip_runtime.h>

#define NN 100000
#define NE 1600000
#define DD 128
#define BM 64
#define NBLK_SCAN 98   // ceil(NN / 1024)

typedef __attribute__((ext_vector_type(4))) float f32x4;
typedef __attribute__((ext_vector_type(8))) short bf16x8;

__device__ inline unsigned short f2bf(float f) {
    unsigned int x = __builtin_bit_cast(unsigned int, f);
    unsigned int r = x + 0x7fffu + ((x >> 16) & 1u);
    return (unsigned short)(r >> 16);
}
__device__ inline float bf_lo(unsigned int u) { return __builtin_bit_cast(float, u << 16); }
__device__ inline float bf_hi(unsigned int u) { return __builtin_bit_cast(float, u & 0xffff0000u); }
__device__ inline unsigned int packbf(float a, float b) {
    return (unsigned int)f2bf(a) | ((unsigned int)f2bf(b) << 16);
}

__device__ inline void load_g2l_16(const void* gsrc, void* ldst) {
    __builtin_amdgcn_global_load_lds(
        (const __attribute__((address_space(1))) void*)(uintptr_t)gsrc,
        (__attribute__((address_space(3))) void*)(uintptr_t)ldst,
        16, 0, 0);
}

// ---------------- CSR build ----------------

__global__ __launch_bounds__(256) void hist_kernel(const int* __restrict__ row,
                                                   int* __restrict__ deg) {
    int i = blockIdx.x * blockDim.x + threadIdx.x;
    int stride = gridDim.x * blockDim.x;
    for (; i < NE; i += stride) atomicAdd(&deg[row[i]], 1);
}

__global__ __launch_bounds__(256) void scanA_kernel(const int* __restrict__ deg,
                                                    int* __restrict__ bsum) {
    __shared__ int red[256];
    int base = blockIdx.x * 1024;
    int t = threadIdx.x;
    int s = 0;
#pragma unroll
    for (int k = 0; k < 4; ++k) {
        int i = base + t * 4 + k;
        if (i < NN) s += deg[i];
    }
    red[t] = s;
    __syncthreads();
    for (int off = 128; off > 0; off >>= 1) {
        if (t < off) red[t] += red[t + off];
        __syncthreads();
    }
    if (t == 0) bsum[blockIdx.x] = red[0];
}

// exclusive scan of the 98 block sums, one block
__global__ __launch_bounds__(128) void scanB_kernel(int* __restrict__ bsum) {
    __shared__ int sm[128];
    int t = threadIdx.x;
    sm[t] = (t < NBLK_SCAN) ? bsum[t] : 0;
    __syncthreads();
    for (int off = 1; off < 128; off <<= 1) {
        int add = (t >= off) ? sm[t - off] : 0;
        __syncthreads();
        sm[t] += add;
        __syncthreads();
    }
    if (t < NBLK_SCAN) bsum[t] = (t > 0) ? sm[t - 1] : 0;
}

__global__ __launch_bounds__(256) void scanC_kernel(const int* __restrict__ deg,
                                                    const int* __restrict__ bsum,
                                                    int* __restrict__ offs) {
    __shared__ int tsum[256];
    int base = blockIdx.x * 1024;
    int t = threadIdx.x;
    int v[4];
    int s = 0;
#pragma unroll
    for (int k = 0; k < 4; ++k) {
        int i = base + t * 4 + k;
        v[k] = (i < NN) ? deg[i] : 0;
        s += v[k];
    }
    tsum[t] = s;
    __syncthreads();
    for (int off = 1; off < 256; off <<= 1) {
        int add = (t >= off) ? tsum[t - off] : 0;
        __syncthreads();
        tsum[t] += add;
        __syncthreads();
    }
    int pre = bsum[blockIdx.x] + ((t > 0) ? tsum[t - 1] : 0);
#pragma unroll
    for (int k = 0; k < 4; ++k) {
        int i = base + t * 4 + k;
        pre += v[k];
        if (i < NN) offs[i + 1] = pre;
    }
    if (blockIdx.x == 0 && t == 0) offs[0] = 0;
}

__global__ __launch_bounds__(256) void scatter_kernel(const int* __restrict__ row,
                                                      const int* __restrict__ col,
                                                      const int* __restrict__ offs,
                                                      int* __restrict__ cursor,
                                                      int* __restrict__ csr_col) {
    int i = blockIdx.x * blockDim.x + threadIdx.x;
    int stride = gridDim.x * blockDim.x;
    for (; i < NE; i += stride) {
        int r = row[i];
        int p = offs[r] + atomicAdd(&cursor[r], 1);
        csr_col[p] = col[i];
    }
}

// ---------------- dtype conversion ----------------

__global__ __launch_bounds__(256) void conv_x_kernel(const float* __restrict__ x,
                                                     unsigned short* __restrict__ xb) {
    int i = blockIdx.x * 256 + threadIdx.x;
    int stride = gridDim.x * 256;
    const int n4 = NN * DD / 4;
    for (; i < n4; i += stride) {
        float4 v = reinterpret_cast<const float4*>(x)[i];
        ushort4 o;
        o.x = f2bf(v.x); o.y = f2bf(v.y); o.z = f2bf(v.z); o.w = f2bf(v.w);
        reinterpret_cast<ushort4*>(xb)[i] = o;
    }
}

// all 6 weight matrices, transposed to bf16 in one launch: wt[i][c][k] = bf16(Wi[k][c])
__global__ __launch_bounds__(256) void conv_w_all(const float* __restrict__ w0,
                                                  const float* __restrict__ w1,
                                                  const float* __restrict__ w2,
                                                  const float* __restrict__ w3,
                                                  const float* __restrict__ w4,
                                                  const float* __restrict__ w5,
                                                  unsigned short* __restrict__ wtall) {
    int t = blockIdx.x * 256 + threadIdx.x;   // 0 .. 6*16384-1
    int i = t >> 14;
    int r = t & 16383;
    const float* W = (i == 0) ? w0 : (i == 1) ? w1 : (i == 2) ? w2
                    : (i == 3) ? w3 : (i == 4) ? w4 : w5;
    int c = r >> 7, k = r & 127;
    wtall[t] = f2bf(W[k * DD + c]);
}

// ---------------- per-layer compute ----------------

// mean aggregation over bf16 h: 16 lanes per node, 16B per lane, 4-deep unroll
__global__ __launch_bounds__(256) void aggregate_bf16(const unsigned short* __restrict__ hb,
                                                      const int* __restrict__ offs,
                                                      const int* __restrict__ csr_col,
                                                      unsigned short* __restrict__ aggb) {
    int node = blockIdx.x * 16 + (threadIdx.x >> 4);
    if (node >= NN) return;
    int lane = threadIdx.x & 15;
    int s = offs[node], e = offs[node + 1];
    float a0 = 0, a1 = 0, a2 = 0, a3 = 0, a4 = 0, a5 = 0, a6 = 0, a7 = 0;
    int p = s;
    for (; p + 4 <= e; p += 4) {
        int c0 = csr_col[p + 0];
        int c1 = csr_col[p + 1];
        int c2 = csr_col[p + 2];
        int c3 = csr_col[p + 3];
        uint4 v0 = *reinterpret_cast<const uint4*>(hb + (size_t)c0 * DD + lane * 8);
        uint4 v1 = *reinterpret_cast<const uint4*>(hb + (size_t)c1 * DD + lane * 8);
        uint4 v2 = *reinterpret_cast<const uint4*>(hb + (size_t)c2 * DD + lane * 8);
        uint4 v3 = *reinterpret_cast<const uint4*>(hb + (size_t)c3 * DD + lane * 8);
        a0 += (bf_lo(v0.x) + bf_lo(v1.x)) + (bf_lo(v2.x) + bf_lo(v3.x));
        a1 += (bf_hi(v0.x) + bf_hi(v1.x)) + (bf_hi(v2.x) + bf_hi(v3.x));
        a2 += (bf_lo(v0.y) + bf_lo(v1.y)) + (bf_lo(v2.y) + bf_lo(v3.y));
        a3 += (bf_hi(v0.y) + bf_hi(v1.y)) + (bf_hi(v2.y) + bf_hi(v3.y));
        a4 += (bf_lo(v0.z) + bf_lo(v1.z)) + (bf_lo(v2.z) + bf_lo(v3.z));
        a5 += (bf_hi(v0.z) + bf_hi(v1.z)) + (bf_hi(v2.z) + bf_hi(v3.z));
        a6 += (bf_lo(v0.w) + bf_lo(v1.w)) + (bf_lo(v2.w) + bf_lo(v3.w));
        a7 += (bf_hi(v0.w) + bf_hi(v1.w)) + (bf_hi(v2.w) + bf_hi(v3.w));
    }
    for (; p < e; ++p) {
        int c = csr_col[p];
        uint4 v = *reinterpret_cast<const uint4*>(hb + (size_t)c * DD + lane * 8);
        a0 += bf_lo(v.x); a1 += bf_hi(v.x);
        a2 += bf_lo(v.y); a3 += bf_hi(v.y);
        a4 += bf_lo(v.z); a5 += bf_hi(v.z);
        a6 += bf_lo(v.w); a7 += bf_hi(v.w);
    }
    float inv = (e > s) ? (1.0f / (float)(e - s)) : 0.0f;
    uint4 o;
    o.x = packbf(a0 * inv, a1 * inv);
    o.y = packbf(a2 * inv, a3 * inv);
    o.z = packbf(a4 * inv, a5 * inv);
    o.w = packbf(a6 * inv, a7 * inv);
    *reinterpret_cast<uint4*>(aggb + (size_t)node * DD + lane * 8) = o;
}

// out[64-row tile] = relu(A @ Wl + H @ Wr + b), MFMA 16x16x32 bf16.
__global__ __launch_bounds__(256) void mfma_gemm_kernel(
    const unsigned short* __restrict__ Ab, const unsigned short* __restrict__ Hb,
    const unsigned short* __restrict__ WlT, const unsigned short* __restrict__ WrT,
    const float* __restrict__ bias, float* __restrict__ out,
    unsigned short* __restrict__ hbn) {
    __shared__ unsigned short Alds[BM * DD];
    __shared__ unsigned short Hlds[BM * DD];
    const int row0 = blockIdx.x * BM;
    const int tid = threadIdx.x;
    const int w = tid >> 6, l = tid & 63;

    const char* Asrc = (const char*)(Ab + (size_t)row0 * DD);
    const char* Hsrc = (const char*)(Hb + (size_t)row0 * DD);
    char* AldsB = (char*)Alds;
    char* HldsB = (char*)Hlds;

    // stage 16KB A + 16KB H; each wave fills a 4KB span of each
#pragma unroll
    for (int j = 0; j < 4; ++j) {
        int base = w * 4096 + j * 1024;
        int doff = base + l * 16;
        int soff = doff ^ (((doff >> 8) & 7) << 4);   // inverse swizzle on source
        if (row0 + (doff >> 8) < NN) {
            load_g2l_16(Asrc + soff, AldsB + base);
            load_g2l_16(Hsrc + soff, HldsB + base);
        }
    }
    __syncthreads();

    const int wr = w & 1, wc = w >> 1;
    const int lrow = l & 15, lg = l >> 4;

    f32x4 acc[2][4];
#pragma unroll
    for (int m = 0; m < 2; ++m)
#pragma unroll
        for (int n = 0; n < 4; ++n) acc[m][n] = (f32x4){0.f, 0.f, 0.f, 0.f};

    float bv[4];
#pragma unroll
    for (int n = 0; n < 4; ++n) bv[n] = bias[wc * 64 + n * 16 + lrow];

#pragma unroll
    for (int kb = 0; kb < 4; ++kb) {
        const int kbyte = kb * 64 + lg * 16;
        bf16x8 aA[2], aH[2];
#pragma unroll
        for (int m = 0; m < 2; ++m) {
            int rloc = wr * 32 + m * 16 + lrow;
            int off = (rloc << 8) + kbyte;
            off ^= (rloc & 7) << 4;
            aA[m] = *reinterpret_cast<const bf16x8*>(AldsB + off);
            aH[m] = *reinterpret_cast<const bf16x8*>(HldsB + off);
        }
        bf16x8 bL[4], bR[4];
#pragma unroll
        for (int n = 0; n < 4; ++n) {
            size_t woff = ((size_t)(wc * 64 + n * 16 + lrow) << 7) + kb * 32 + lg * 8;
            bL[n] = *reinterpret_cast<const bf16x8*>(WlT + woff);
            bR[n] = *reinterpret_cast<const bf16x8*>(WrT + woff);
        }
#pragma unroll
        for (int m = 0; m < 2; ++m)
#pragma unroll
            for (int n = 0; n < 4; ++n) {
                acc[m][n] = __builtin_amdgcn_mfma_f32_16x16x32_bf16(aA[m], bL[n], acc[m][n], 0, 0, 0);
                acc[m][n] = __builtin_amdgcn_mfma_f32_16x16x32_bf16(aH[m], bR[n], acc[m][n], 0, 0, 0);
            }
    }

#pragma unroll
    for (int m = 0; m < 2; ++m) {
        int grow_base = row0 + wr * 32 + m * 16 + lg * 4;
#pragma unroll
        for (int n = 0; n < 4; ++n) {
            int c = wc * 64 + n * 16 + lrow;
#pragma unroll
            for (int j = 0; j < 4; ++j) {
                int gr = grow_base + j;
                if (gr < NN) {
                    float v = acc[m][n][j] + bv[n];
                    v = fmaxf(v, 0.0f);
                    __builtin_nontemporal_store(v, &out[(size_t)gr * DD + c]);
                    if (hbn) hbn[(size_t)gr * DD + c] = f2bf(v);
                }
            }
        }
    }
}

extern "C" void kernel_launch(void* const* d_in, const int* in_sizes, int n_in,
                              void* d_out, int out_size, void* d_ws, size_t ws_size,
                              hipStream_t stream) {
    const float* x = (const float*)d_in[0];
    const int* ei = (const int*)d_in[1];
    const int* row = ei;        // dst
    const int* col = ei + NE;   // src
    const float* Wl[3] = {(const float*)d_in[2], (const float*)d_in[5], (const float*)d_in[8]};
    const float* Wr[3] = {(const float*)d_in[3], (const float*)d_in[6], (const float*)d_in[9]};
    const float* bb[3] = {(const float*)d_in[4], (const float*)d_in[7], (const float*)d_in[10]};
    float* out = (float*)d_out;

    char* ws = (char*)d_ws;
    auto carve = [&](size_t bytes) {
        char* p = ws;
        ws += (bytes + 255) & ~(size_t)255;
        return p;
    };
    unsigned short* buf0 = (unsigned short*)carve((size_t)NN * DD * 2);  // xb, reused as h2b
    unsigned short* buf1 = (unsigned short*)carve((size_t)NN * DD * 2);  // h1b
    unsigned short* aggb = (unsigned short*)carve((size_t)NN * DD * 2);
    unsigned short* wtall = (unsigned short*)carve((size_t)6 * DD * DD * 2);
    int* deg     = (int*)carve((size_t)NN * sizeof(int));
    int* cursor  = (int*)carve((size_t)NN * sizeof(int));
    int* offs    = (int*)carve((size_t)(NN + 1) * sizeof(int));
    int* bsum    = (int*)carve(128 * sizeof(int));
    int* csr_col = (int*)carve((size_t)NE * sizeof(int));

    hipMemsetAsync(deg, 0, (size_t)NN * sizeof(int), stream);
    hipMemsetAsync(cursor, 0, (size_t)NN * sizeof(int), stream);

    conv_x_kernel<<<2048, 256, 0, stream>>>(x, buf0);
    conv_w_all<<<(6 * DD * DD) / 256, 256, 0, stream>>>(
        Wl[0], Wr[0], Wl[1], Wr[1], Wl[2], Wr[2], wtall);

    hist_kernel<<<2048, 256, 0, stream>>>(row, deg);
    scanA_kernel<<<NBLK_SCAN, 256, 0, stream>>>(deg, bsum);
    scanB_kernel<<<1, 128, 0, stream>>>(bsum);
    scanC_kernel<<<NBLK_SCAN, 256, 0, stream>>>(deg, bsum, offs);
    scatter_kernel<<<2048, 256, 0, stream>>>(row, col, offs, cursor, csr_col);

    const int ngrid = (NN + BM - 1) / BM;   // 1563
    const int agrid = (NN + 15) / 16;       // 6250

    unsigned short* hin = buf0;
    unsigned short* hout = buf1;
    for (int lyr = 0; lyr < 3; ++lyr) {
        float* o = out + (size_t)lyr * NN * DD;
        aggregate_bf16<<<agrid, 256, 0, stream>>>(hin, offs, csr_col, aggb);
        mfma_gemm_kernel<<<ngrid, 256, 0, stream>>>(
            aggb, hin, wtall + (size_t)2 * lyr * DD * DD, wtall + (size_t)(2 * lyr + 1) * DD * DD,
            bb[lyr], o, (lyr < 2) ? hout : (unsigned short*)nullptr);
        unsigned short* t = hin; hin = hout; hout = t;
    }
}

// Round 4
// 385.891 us; speedup vs baseline: 3.0663x; 1.2940x over previous
//
#include <hip/hip_runtime.h>

#define NN 100000
#define NE 1600000
#define DD 128
#define BM 64
#define NPB 256                   // nodes per bucket
#define NBUCK 391                 // ceil(NN / NPB)
#define ECHUNK 8192
#define NBLK_PART 196             // ceil(NE / ECHUNK)
#define CAP 8192                  // LDS staging capacity (mean bucket = 4092 edges)

typedef __attribute__((ext_vector_type(4))) float f32x4;
typedef __attribute__((ext_vector_type(8))) short bf16x8;

__device__ inline unsigned short f2bf(float f) {
    unsigned int x = __builtin_bit_cast(unsigned int, f);
    unsigned int r = x + 0x7fffu + ((x >> 16) & 1u);
    return (unsigned short)(r >> 16);
}
__device__ inline float bf_lo(unsigned int u) { return __builtin_bit_cast(float, u << 16); }
__device__ inline float bf_hi(unsigned int u) { return __builtin_bit_cast(float, u & 0xffff0000u); }
__device__ inline unsigned int packbf(float a, float b) {
    return (unsigned int)f2bf(a) | ((unsigned int)f2bf(b) << 16);
}

__device__ inline void load_g2l_16(const void* gsrc, void* ldst) {
    __builtin_amdgcn_global_load_lds(
        (const __attribute__((address_space(1))) void*)(uintptr_t)gsrc,
        (__attribute__((address_space(3))) void*)(uintptr_t)ldst,
        16, 0, 0);
}

// ---------------- bucketed CSR build ----------------

// A1: global per-bucket histogram via per-block LDS histogram
__global__ __launch_bounds__(256) void bucket_hist(const int* __restrict__ row,
                                                   int* __restrict__ gcnt) {
    __shared__ int cnt[NBUCK];
    for (int i = threadIdx.x; i < NBUCK; i += 256) cnt[i] = 0;
    __syncthreads();
    int base = blockIdx.x * ECHUNK;
    int end = base + ECHUNK; if (end > NE) end = NE;
    for (int i = base + threadIdx.x; i < end; i += 256)
        atomicAdd(&cnt[row[i] >> 8], 1);
    __syncthreads();
    for (int i = threadIdx.x; i < NBUCK; i += 256) {
        int c = cnt[i];
        if (c) atomicAdd(&gcnt[i], c);
    }
}

// scan 391 bucket counts -> gbase[NBUCK+1] (exclusive)
__global__ __launch_bounds__(512) void bucket_scan(const int* __restrict__ gcnt,
                                                   int* __restrict__ gbase) {
    __shared__ int sm[512];
    int t = threadIdx.x;
    sm[t] = (t < NBUCK) ? gcnt[t] : 0;
    __syncthreads();
    for (int off = 1; off < 512; off <<= 1) {
        int add = (t >= off) ? sm[t - off] : 0;
        __syncthreads();
        sm[t] += add;
        __syncthreads();
    }
    if (t < NBUCK) gbase[t + 1] = sm[t];
    if (t == 0) gbase[0] = 0;
}

// A2: partition edges into bucket-major ebuf (row,col) pairs
__global__ __launch_bounds__(256) void bucket_scatter(const int* __restrict__ row,
                                                      const int* __restrict__ col,
                                                      const int* __restrict__ gbase,
                                                      int* __restrict__ gcursor,
                                                      uint2* __restrict__ ebuf) {
    __shared__ int cnt[NBUCK];
    __shared__ int base[NBUCK];
    for (int i = threadIdx.x; i < NBUCK; i += 256) cnt[i] = 0;
    __syncthreads();
    int cbase = blockIdx.x * ECHUNK;
    int cend = cbase + ECHUNK; if (cend > NE) cend = NE;
    for (int i = cbase + threadIdx.x; i < cend; i += 256)
        atomicAdd(&cnt[row[i] >> 8], 1);
    __syncthreads();
    for (int i = threadIdx.x; i < NBUCK; i += 256) {
        int c = cnt[i];
        cnt[i] = 0;
        base[i] = c ? (gbase[i] + atomicAdd(&gcursor[i], c)) : 0;
    }
    __syncthreads();
    for (int i = cbase + threadIdx.x; i < cend; i += 256) {
        int r = row[i], c = col[i];
        int b = r >> 8;
        int k = atomicAdd(&cnt[b], 1);
        ebuf[base[b] + k] = uint2{(unsigned)r, (unsigned)c};
    }
}

// B: per-bucket CSR slice built in LDS, streamed out coalesced; also writes offs
__global__ __launch_bounds__(256) void csr_build(const uint2* __restrict__ ebuf,
                                                 const int* __restrict__ gbase,
                                                 int* __restrict__ offs,
                                                 int* __restrict__ csr_col) {
    __shared__ int dcnt[NPB];
    __shared__ int doff[NPB];
    __shared__ int sm[NPB];
    __shared__ int stage[CAP];
    const int b = blockIdx.x;
    const int es = gbase[b], ee = gbase[b + 1];
    const int m = ee - es;
    const int t = threadIdx.x;
    const int nbase = b * NPB;

    dcnt[t] = 0;
    __syncthreads();
    for (int i = es + t; i < ee; i += 256) {
        int ln = (int)ebuf[i].x - nbase;
        atomicAdd(&dcnt[ln], 1);
    }
    __syncthreads();
    sm[t] = dcnt[t];
    __syncthreads();
    for (int off = 1; off < 256; off <<= 1) {
        int add = (t >= off) ? sm[t - off] : 0;
        __syncthreads();
        sm[t] += add;
        __syncthreads();
    }
    doff[t] = sm[t] - dcnt[t];
    int node = nbase + t;
    if (node < NN) offs[node + 1] = es + sm[t];
    if (b == 0 && t == 0) offs[0] = 0;
    dcnt[t] = 0;
    __syncthreads();

    if (m <= CAP) {
        for (int i = es + t; i < ee; i += 256) {
            uint2 e = ebuf[i];
            int ln = (int)e.x - nbase;
            int k = atomicAdd(&dcnt[ln], 1);
            stage[doff[ln] + k] = (int)e.y;
        }
        __syncthreads();
        for (int i = t; i < m; i += 256) csr_col[es + i] = stage[i];
    } else {  // safety fallback (statistically unreachable)
        for (int i = es + t; i < ee; i += 256) {
            uint2 e = ebuf[i];
            int ln = (int)e.x - nbase;
            int k = atomicAdd(&dcnt[ln], 1);
            csr_col[es + doff[ln] + k] = (int)e.y;
        }
    }
}

// ---------------- dtype conversion ----------------

__global__ __launch_bounds__(256) void conv_x_kernel(const float* __restrict__ x,
                                                     unsigned short* __restrict__ xb) {
    int i = blockIdx.x * 256 + threadIdx.x;
    int stride = gridDim.x * 256;
    const int n4 = NN * DD / 4;
    for (; i < n4; i += stride) {
        float4 v = reinterpret_cast<const float4*>(x)[i];
        ushort4 o;
        o.x = f2bf(v.x); o.y = f2bf(v.y); o.z = f2bf(v.z); o.w = f2bf(v.w);
        reinterpret_cast<ushort4*>(xb)[i] = o;
    }
}

// all 6 weight matrices, transposed to bf16 in one launch: wt[i][c][k] = bf16(Wi[k][c])
__global__ __launch_bounds__(256) void conv_w_all(const float* __restrict__ w0,
                                                  const float* __restrict__ w1,
                                                  const float* __restrict__ w2,
                                                  const float* __restrict__ w3,
                                                  const float* __restrict__ w4,
                                                  const float* __restrict__ w5,
                                                  unsigned short* __restrict__ wtall) {
    int t = blockIdx.x * 256 + threadIdx.x;   // 0 .. 6*16384-1
    int i = t >> 14;
    int r = t & 16383;
    const float* W = (i == 0) ? w0 : (i == 1) ? w1 : (i == 2) ? w2
                    : (i == 3) ? w3 : (i == 4) ? w4 : w5;
    int c = r >> 7, k = r & 127;
    wtall[t] = f2bf(W[k * DD + c]);
}

// ---------------- per-layer compute ----------------

// mean aggregation over bf16 h: 16 lanes per node, 16B per lane, 8-deep unroll
__global__ __launch_bounds__(256) void aggregate_bf16(const unsigned short* __restrict__ hb,
                                                      const int* __restrict__ offs,
                                                      const int* __restrict__ csr_col,
                                                      unsigned short* __restrict__ aggb) {
    int node = blockIdx.x * 16 + (threadIdx.x >> 4);
    if (node >= NN) return;
    int lane = threadIdx.x & 15;
    int s = offs[node], e = offs[node + 1];
    float a0 = 0, a1 = 0, a2 = 0, a3 = 0, a4 = 0, a5 = 0, a6 = 0, a7 = 0;
    int p = s;
    for (; p + 8 <= e; p += 8) {
        uint4 v[8];
#pragma unroll
        for (int q = 0; q < 8; ++q) {
            int c = csr_col[p + q];
            v[q] = *reinterpret_cast<const uint4*>(hb + (size_t)c * DD + lane * 8);
        }
#pragma unroll
        for (int q = 0; q < 8; ++q) {
            a0 += bf_lo(v[q].x); a1 += bf_hi(v[q].x);
            a2 += bf_lo(v[q].y); a3 += bf_hi(v[q].y);
            a4 += bf_lo(v[q].z); a5 += bf_hi(v[q].z);
            a6 += bf_lo(v[q].w); a7 += bf_hi(v[q].w);
        }
    }
    for (; p < e; ++p) {
        int c = csr_col[p];
        uint4 v = *reinterpret_cast<const uint4*>(hb + (size_t)c * DD + lane * 8);
        a0 += bf_lo(v.x); a1 += bf_hi(v.x);
        a2 += bf_lo(v.y); a3 += bf_hi(v.y);
        a4 += bf_lo(v.z); a5 += bf_hi(v.z);
        a6 += bf_lo(v.w); a7 += bf_hi(v.w);
    }
    float inv = (e > s) ? (1.0f / (float)(e - s)) : 0.0f;
    uint4 o;
    o.x = packbf(a0 * inv, a1 * inv);
    o.y = packbf(a2 * inv, a3 * inv);
    o.z = packbf(a4 * inv, a5 * inv);
    o.w = packbf(a6 * inv, a7 * inv);
    *reinterpret_cast<uint4*>(aggb + (size_t)node * DD + lane * 8) = o;
}

// out[64-row tile] = relu(A @ Wl + H @ Wr + b), MFMA 16x16x32 bf16.
__global__ __launch_bounds__(256) void mfma_gemm_kernel(
    const unsigned short* __restrict__ Ab, const unsigned short* __restrict__ Hb,
    const unsigned short* __restrict__ WlT, const unsigned short* __restrict__ WrT,
    const float* __restrict__ bias, float* __restrict__ out,
    unsigned short* __restrict__ hbn) {
    __shared__ unsigned short Alds[BM * DD];
    __shared__ unsigned short Hlds[BM * DD];
    const int row0 = blockIdx.x * BM;
    const int tid = threadIdx.x;
    const int w = tid >> 6, l = tid & 63;

    const char* Asrc = (const char*)(Ab + (size_t)row0 * DD);
    const char* Hsrc = (const char*)(Hb + (size_t)row0 * DD);
    char* AldsB = (char*)Alds;
    char* HldsB = (char*)Hlds;

#pragma unroll
    for (int j = 0; j < 4; ++j) {
        int base = w * 4096 + j * 1024;
        int doff = base + l * 16;
        int soff = doff ^ (((doff >> 8) & 7) << 4);   // inverse swizzle on source
        if (row0 + (doff >> 8) < NN) {
            load_g2l_16(Asrc + soff, AldsB + base);
            load_g2l_16(Hsrc + soff, HldsB + base);
        }
    }
    __syncthreads();

    const int wr = w & 1, wc = w >> 1;
    const int lrow = l & 15, lg = l >> 4;

    f32x4 acc[2][4];
#pragma unroll
    for (int m = 0; m < 2; ++m)
#pragma unroll
        for (int n = 0; n < 4; ++n) acc[m][n] = (f32x4){0.f, 0.f, 0.f, 0.f};

    float bv[4];
#pragma unroll
    for (int n = 0; n < 4; ++n) bv[n] = bias[wc * 64 + n * 16 + lrow];

#pragma unroll
    for (int kb = 0; kb < 4; ++kb) {
        const int kbyte = kb * 64 + lg * 16;
        bf16x8 aA[2], aH[2];
#pragma unroll
        for (int m = 0; m < 2; ++m) {
            int rloc = wr * 32 + m * 16 + lrow;
            int off = (rloc << 8) + kbyte;
            off ^= (rloc & 7) << 4;
            aA[m] = *reinterpret_cast<const bf16x8*>(AldsB + off);
            aH[m] = *reinterpret_cast<const bf16x8*>(HldsB + off);
        }
        bf16x8 bL[4], bR[4];
#pragma unroll
        for (int n = 0; n < 4; ++n) {
            size_t woff = ((size_t)(wc * 64 + n * 16 + lrow) << 7) + kb * 32 + lg * 8;
            bL[n] = *reinterpret_cast<const bf16x8*>(WlT + woff);
            bR[n] = *reinterpret_cast<const bf16x8*>(WrT + woff);
        }
#pragma unroll
        for (int m = 0; m < 2; ++m)
#pragma unroll
            for (int n = 0; n < 4; ++n) {
                acc[m][n] = __builtin_amdgcn_mfma_f32_16x16x32_bf16(aA[m], bL[n], acc[m][n], 0, 0, 0);
                acc[m][n] = __builtin_amdgcn_mfma_f32_16x16x32_bf16(aH[m], bR[n], acc[m][n], 0, 0, 0);
            }
    }

#pragma unroll
    for (int m = 0; m < 2; ++m) {
        int grow_base = row0 + wr * 32 + m * 16 + lg * 4;
#pragma unroll
        for (int n = 0; n < 4; ++n) {
            int c = wc * 64 + n * 16 + lrow;
#pragma unroll
            for (int j = 0; j < 4; ++j) {
                int gr = grow_base + j;
                if (gr < NN) {
                    float v = acc[m][n][j] + bv[n];
                    v = fmaxf(v, 0.0f);
                    __builtin_nontemporal_store(v, &out[(size_t)gr * DD + c]);
                    if (hbn) hbn[(size_t)gr * DD + c] = f2bf(v);
                }
            }
        }
    }
}

extern "C" void kernel_launch(void* const* d_in, const int* in_sizes, int n_in,
                              void* d_out, int out_size, void* d_ws, size_t ws_size,
                              hipStream_t stream) {
    const float* x = (const float*)d_in[0];
    const int* ei = (const int*)d_in[1];
    const int* row = ei;        // dst
    const int* col = ei + NE;   // src
    const float* Wl[3] = {(const float*)d_in[2], (const float*)d_in[5], (const float*)d_in[8]};
    const float* Wr[3] = {(const float*)d_in[3], (const float*)d_in[6], (const float*)d_in[9]};
    const float* bb[3] = {(const float*)d_in[4], (const float*)d_in[7], (const float*)d_in[10]};
    float* out = (float*)d_out;

    char* ws = (char*)d_ws;
    auto carve = [&](size_t bytes) {
        char* p = ws;
        ws += (bytes + 255) & ~(size_t)255;
        return p;
    };
    unsigned short* buf0 = (unsigned short*)carve((size_t)NN * DD * 2);
    unsigned short* buf1 = (unsigned short*)carve((size_t)NN * DD * 2);
    unsigned short* aggb = (unsigned short*)carve((size_t)NN * DD * 2);
    unsigned short* wtall = (unsigned short*)carve((size_t)6 * DD * DD * 2);
    int* gcnt    = (int*)carve((size_t)2 * NBUCK * sizeof(int));  // gcnt + gcursor
    int* gcursor = gcnt + NBUCK;
    int* gbase   = (int*)carve((size_t)(NBUCK + 1) * sizeof(int));
    int* offs    = (int*)carve((size_t)(NN + 1) * sizeof(int));
    uint2* ebuf  = (uint2*)carve((size_t)NE * sizeof(uint2));     // 12.8 MB
    int* csr_col = (int*)carve((size_t)NE * sizeof(int));         // 6.4 MB

    hipMemsetAsync(gcnt, 0, (size_t)2 * NBUCK * sizeof(int), stream);

    conv_x_kernel<<<2048, 256, 0, stream>>>(x, buf0);
    conv_w_all<<<(6 * DD * DD) / 256, 256, 0, stream>>>(
        Wl[0], Wr[0], Wl[1], Wr[1], Wl[2], Wr[2], wtall);

    bucket_hist<<<NBLK_PART, 256, 0, stream>>>(row, gcnt);
    bucket_scan<<<1, 512, 0, stream>>>(gcnt, gbase);
    bucket_scatter<<<NBLK_PART, 256, 0, stream>>>(row, col, gbase, gcursor, ebuf);
    csr_build<<<NBUCK, 256, 0, stream>>>(ebuf, gbase, offs, csr_col);

    const int ngrid = (NN + BM - 1) / BM;   // 1563
    const int agrid = (NN + 15) / 16;       // 6250

    unsigned short* hin = buf0;
    unsigned short* hout = buf1;
    for (int lyr = 0; lyr < 3; ++lyr) {
        float* o = out + (size_t)lyr * NN * DD;
        aggregate_bf16<<<agrid, 256, 0, stream>>>(hin, offs, csr_col, aggb);
        mfma_gemm_kernel<<<ngrid, 256, 0, stream>>>(
            aggb, hin, wtall + (size_t)2 * lyr * DD * DD, wtall + (size_t)(2 * lyr + 1) * DD * DD,
            bb[lyr], o, (lyr < 2) ? hout : (unsigned short*)nullptr);
        unsigned short* t = hin; hin = hout; hout = t;
    }
}

// Round 5
// 350.476 us; speedup vs baseline: 3.3761x; 1.1010x over previous
//
#include <hip/hip_runtime.h>

#define NN 100000
#define NE 1600000
#define DD 128
#define BM 64
#define NPB 256                   // nodes per bucket
#define NBUCK 391                 // ceil(NN / NPB)
#define ECHUNK 8192
#define NBLK_PART 196             // ceil(NE / ECHUNK)
#define CAP 8192                  // LDS staging capacity (mean bucket = 4092 edges)
#define CVX_BLK 800
#define CVW_BLK 384

typedef __attribute__((ext_vector_type(4))) float f32x4;
typedef __attribute__((ext_vector_type(8))) short bf16x8;

__device__ inline unsigned short f2bf(float f) {
    unsigned int x = __builtin_bit_cast(unsigned int, f);
    unsigned int r = x + 0x7fffu + ((x >> 16) & 1u);
    return (unsigned short)(r >> 16);
}
__device__ inline float bf_lo(unsigned int u) { return __builtin_bit_cast(float, u << 16); }
__device__ inline float bf_hi(unsigned int u) { return __builtin_bit_cast(float, u & 0xffff0000u); }
__device__ inline unsigned int packbf(float a, float b) {
    return (unsigned int)f2bf(a) | ((unsigned int)f2bf(b) << 16);
}

__device__ inline void load_g2l_16(const void* gsrc, void* ldst) {
    __builtin_amdgcn_global_load_lds(
        (const __attribute__((address_space(1))) void*)(uintptr_t)gsrc,
        (__attribute__((address_space(3))) void*)(uintptr_t)ldst,
        16, 0, 0);
}

// ---------------- fused prep: conv_x + conv_w + bucket_hist ----------------

__global__ __launch_bounds__(256) void prep_kernel(
    const float* __restrict__ x, unsigned short* __restrict__ xb,
    const float* __restrict__ w0, const float* __restrict__ w1,
    const float* __restrict__ w2, const float* __restrict__ w3,
    const float* __restrict__ w4, const float* __restrict__ w5,
    unsigned short* __restrict__ wtall,
    const int* __restrict__ row, int* __restrict__ gcnt) {
    __shared__ int cnt[NBUCK];
    const int b = blockIdx.x;
    if (b < CVX_BLK) {
        int i = b * 256 + threadIdx.x;
        const int n4 = NN * DD / 4;
        for (; i < n4; i += CVX_BLK * 256) {
            float4 v = reinterpret_cast<const float4*>(x)[i];
            ushort4 o;
            o.x = f2bf(v.x); o.y = f2bf(v.y); o.z = f2bf(v.z); o.w = f2bf(v.w);
            reinterpret_cast<ushort4*>(xb)[i] = o;
        }
    } else if (b < CVX_BLK + CVW_BLK) {
        int t = (b - CVX_BLK) * 256 + threadIdx.x;   // 0 .. 6*16384-1
        int i = t >> 14;
        int r = t & 16383;
        const float* W = (i == 0) ? w0 : (i == 1) ? w1 : (i == 2) ? w2
                        : (i == 3) ? w3 : (i == 4) ? w4 : w5;
        int c = r >> 7, k = r & 127;
        wtall[t] = f2bf(W[k * DD + c]);
    } else {
        for (int i = threadIdx.x; i < NBUCK; i += 256) cnt[i] = 0;
        __syncthreads();
        int base = (b - CVX_BLK - CVW_BLK) * ECHUNK;
        int end = base + ECHUNK; if (end > NE) end = NE;
        for (int i = base + threadIdx.x; i < end; i += 256)
            atomicAdd(&cnt[row[i] >> 8], 1);
        __syncthreads();
        for (int i = threadIdx.x; i < NBUCK; i += 256) {
            int c = cnt[i];
            if (c) atomicAdd(&gcnt[i], c);
        }
    }
}

// ---------------- bucketed CSR build ----------------

__global__ __launch_bounds__(512) void bucket_scan(const int* __restrict__ gcnt,
                                                   int* __restrict__ gbase) {
    __shared__ int sm[512];
    int t = threadIdx.x;
    sm[t] = (t < NBUCK) ? gcnt[t] : 0;
    __syncthreads();
    for (int off = 1; off < 512; off <<= 1) {
        int add = (t >= off) ? sm[t - off] : 0;
        __syncthreads();
        sm[t] += add;
        __syncthreads();
    }
    if (t < NBUCK) gbase[t + 1] = sm[t];
    if (t == 0) gbase[0] = 0;
}

__global__ __launch_bounds__(256) void bucket_scatter(const int* __restrict__ row,
                                                      const int* __restrict__ col,
                                                      const int* __restrict__ gbase,
                                                      int* __restrict__ gcursor,
                                                      uint2* __restrict__ ebuf) {
    __shared__ int cnt[NBUCK];
    __shared__ int base[NBUCK];
    for (int i = threadIdx.x; i < NBUCK; i += 256) cnt[i] = 0;
    __syncthreads();
    int cbase = blockIdx.x * ECHUNK;
    int cend = cbase + ECHUNK; if (cend > NE) cend = NE;
    for (int i = cbase + threadIdx.x; i < cend; i += 256)
        atomicAdd(&cnt[row[i] >> 8], 1);
    __syncthreads();
    for (int i = threadIdx.x; i < NBUCK; i += 256) {
        int c = cnt[i];
        cnt[i] = 0;
        base[i] = c ? (gbase[i] + atomicAdd(&gcursor[i], c)) : 0;
    }
    __syncthreads();
    for (int i = cbase + threadIdx.x; i < cend; i += 256) {
        int r = row[i], c = col[i];
        int b = r >> 8;
        int k = atomicAdd(&cnt[b], 1);
        ebuf[base[b] + k] = uint2{(unsigned)r, (unsigned)c};
    }
}

__global__ __launch_bounds__(256) void csr_build(const uint2* __restrict__ ebuf,
                                                 const int* __restrict__ gbase,
                                                 int* __restrict__ offs,
                                                 int* __restrict__ csr_col) {
    __shared__ int dcnt[NPB];
    __shared__ int doff[NPB];
    __shared__ int sm[NPB];
    __shared__ int stage[CAP];
    const int b = blockIdx.x;
    const int es = gbase[b], ee = gbase[b + 1];
    const int m = ee - es;
    const int t = threadIdx.x;
    const int nbase = b * NPB;

    dcnt[t] = 0;
    __syncthreads();
    for (int i = es + t; i < ee; i += 256) {
        int ln = (int)ebuf[i].x - nbase;
        atomicAdd(&dcnt[ln], 1);
    }
    __syncthreads();
    sm[t] = dcnt[t];
    __syncthreads();
    for (int off = 1; off < 256; off <<= 1) {
        int add = (t >= off) ? sm[t - off] : 0;
        __syncthreads();
        sm[t] += add;
        __syncthreads();
    }
    doff[t] = sm[t] - dcnt[t];
    int node = nbase + t;
    if (node < NN) offs[node + 1] = es + sm[t];
    if (b == 0 && t == 0) offs[0] = 0;
    dcnt[t] = 0;
    __syncthreads();

    if (m <= CAP) {
        for (int i = es + t; i < ee; i += 256) {
            uint2 e = ebuf[i];
            int ln = (int)e.x - nbase;
            int k = atomicAdd(&dcnt[ln], 1);
            stage[doff[ln] + k] = (int)e.y;
        }
        __syncthreads();
        for (int i = t; i < m; i += 256) csr_col[es + i] = stage[i];
    } else {
        for (int i = es + t; i < ee; i += 256) {
            uint2 e = ebuf[i];
            int ln = (int)e.x - nbase;
            int k = atomicAdd(&dcnt[ln], 1);
            csr_col[es + doff[ln] + k] = (int)e.y;
        }
    }
}

// ---------------- fused layer: aggregate + dual GEMM + epilogue ----------------

// per 64-row tile: gather-mean neighbors into swizzled A LDS tile (bf16),
// stage H via global_load_lds, MFMA relu(A@Wl + H@Wr + b), stream out via LDS.
__global__ __launch_bounds__(256) void fused_layer(
    const unsigned short* __restrict__ hb,
    const int* __restrict__ offs, const int* __restrict__ csr_col,
    const unsigned short* __restrict__ WlT, const unsigned short* __restrict__ WrT,
    const float* __restrict__ bias, float* __restrict__ out,
    unsigned short* __restrict__ hbn) {
    __shared__ uint4 smem4[2048];            // 32KB: A(16KB) + H(16KB), reused as fp32 out tile
    char* AldsB = (char*)smem4;
    char* HldsB = AldsB + 16384;
    const int row0 = blockIdx.x * BM;
    const int tid = threadIdx.x;
    const int w = tid >> 6, l = tid & 63;

    // 1) issue H staging: 16KB, each wave a 4KB span
    const char* Hsrc = (const char*)(hb + (size_t)row0 * DD);
#pragma unroll
    for (int j = 0; j < 4; ++j) {
        int base = w * 4096 + j * 1024;
        int doff = base + l * 16;
        int soff = doff ^ (((doff >> 8) & 7) << 4);   // inverse swizzle on source
        if (row0 + (doff >> 8) < NN) load_g2l_16(Hsrc + soff, HldsB + base);
    }

    // 2) gather-aggregate A into LDS (bf16, swizzled), 16 lanes per node
    const int g16 = tid >> 4, lane = tid & 15;
    for (int i = 0; i < 4; ++i) {
        const int rloc = g16 * 4 + i;
        const int node = row0 + rloc;
        float a0 = 0, a1 = 0, a2 = 0, a3 = 0, a4 = 0, a5 = 0, a6 = 0, a7 = 0;
        float inv = 0.0f;
        if (node < NN) {
            int s = offs[node], e = offs[node + 1];
            int p = s;
            for (; p + 8 <= e; p += 8) {
                uint4 v[8];
#pragma unroll
                for (int q = 0; q < 8; ++q) {
                    int c = csr_col[p + q];
                    v[q] = *reinterpret_cast<const uint4*>(hb + (size_t)c * DD + lane * 8);
                }
#pragma unroll
                for (int q = 0; q < 8; ++q) {
                    a0 += bf_lo(v[q].x); a1 += bf_hi(v[q].x);
                    a2 += bf_lo(v[q].y); a3 += bf_hi(v[q].y);
                    a4 += bf_lo(v[q].z); a5 += bf_hi(v[q].z);
                    a6 += bf_lo(v[q].w); a7 += bf_hi(v[q].w);
                }
            }
            for (; p < e; ++p) {
                int c = csr_col[p];
                uint4 v = *reinterpret_cast<const uint4*>(hb + (size_t)c * DD + lane * 8);
                a0 += bf_lo(v.x); a1 += bf_hi(v.x);
                a2 += bf_lo(v.y); a3 += bf_hi(v.y);
                a4 += bf_lo(v.z); a5 += bf_hi(v.z);
                a6 += bf_lo(v.w); a7 += bf_hi(v.w);
            }
            inv = (e > s) ? (1.0f / (float)(e - s)) : 0.0f;
        }
        uint4 o;
        o.x = packbf(a0 * inv, a1 * inv);
        o.y = packbf(a2 * inv, a3 * inv);
        o.z = packbf(a4 * inv, a5 * inv);
        o.w = packbf(a6 * inv, a7 * inv);
        int off = (rloc << 8) + ((lane * 16) ^ ((rloc & 7) << 4));
        *reinterpret_cast<uint4*>(AldsB + off) = o;
    }
    __syncthreads();

    // 3) MFMA
    const int wr = w & 1, wc = w >> 1;
    const int lrow = l & 15, lg = l >> 4;

    f32x4 acc[2][4];
#pragma unroll
    for (int m = 0; m < 2; ++m)
#pragma unroll
        for (int n = 0; n < 4; ++n) acc[m][n] = (f32x4){0.f, 0.f, 0.f, 0.f};

    float bv[4];
#pragma unroll
    for (int n = 0; n < 4; ++n) bv[n] = bias[wc * 64 + n * 16 + lrow];

#pragma unroll
    for (int kb = 0; kb < 4; ++kb) {
        const int kbyte = kb * 64 + lg * 16;
        bf16x8 aA[2], aH[2];
#pragma unroll
        for (int m = 0; m < 2; ++m) {
            int rloc = wr * 32 + m * 16 + lrow;
            int off = (rloc << 8) + kbyte;
            off ^= (rloc & 7) << 4;
            aA[m] = *reinterpret_cast<const bf16x8*>(AldsB + off);
            aH[m] = *reinterpret_cast<const bf16x8*>(HldsB + off);
        }
        bf16x8 bL[4], bR[4];
#pragma unroll
        for (int n = 0; n < 4; ++n) {
            size_t woff = ((size_t)(wc * 64 + n * 16 + lrow) << 7) + kb * 32 + lg * 8;
            bL[n] = *reinterpret_cast<const bf16x8*>(WlT + woff);
            bR[n] = *reinterpret_cast<const bf16x8*>(WrT + woff);
        }
#pragma unroll
        for (int m = 0; m < 2; ++m)
#pragma unroll
            for (int n = 0; n < 4; ++n) {
                acc[m][n] = __builtin_amdgcn_mfma_f32_16x16x32_bf16(aA[m], bL[n], acc[m][n], 0, 0, 0);
                acc[m][n] = __builtin_amdgcn_mfma_f32_16x16x32_bf16(aH[m], bR[n], acc[m][n], 0, 0, 0);
            }
    }

    // 4) epilogue: bias+relu into fp32 LDS tile, then stream coalesced
    __syncthreads();
    float* otile = (float*)smem4;
#pragma unroll
    for (int m = 0; m < 2; ++m) {
        int rb = wr * 32 + m * 16 + lg * 4;
#pragma unroll
        for (int n = 0; n < 4; ++n) {
            int c = wc * 64 + n * 16 + lrow;
#pragma unroll
            for (int j = 0; j < 4; ++j)
                otile[(rb + j) * DD + c] = fmaxf(acc[m][n][j] + bv[n], 0.0f);
        }
    }
    __syncthreads();
    const f32x4* t4 = (const f32x4*)smem4;
#pragma unroll
    for (int it = 0; it < 8; ++it) {
        int idx = it * 256 + tid;        // float4 index in 64x128 tile (2048 total)
        int r = idx >> 5;
        int gr = row0 + r;
        if (gr < NN) {
            f32x4 v = t4[idx];
            __builtin_nontemporal_store(v, (f32x4*)out + (size_t)gr * 32 + (idx & 31));
            if (hbn) {
                uint2 pk;
                pk.x = packbf(v[0], v[1]);
                pk.y = packbf(v[2], v[3]);
                *((uint2*)hbn + (size_t)gr * 32 + (idx & 31)) = pk;
            }
        }
    }
}

extern "C" void kernel_launch(void* const* d_in, const int* in_sizes, int n_in,
                              void* d_out, int out_size, void* d_ws, size_t ws_size,
                              hipStream_t stream) {
    const float* x = (const float*)d_in[0];
    const int* ei = (const int*)d_in[1];
    const int* row = ei;        // dst
    const int* col = ei + NE;   // src
    const float* Wl[3] = {(const float*)d_in[2], (const float*)d_in[5], (const float*)d_in[8]};
    const float* Wr[3] = {(const float*)d_in[3], (const float*)d_in[6], (const float*)d_in[9]};
    const float* bb[3] = {(const float*)d_in[4], (const float*)d_in[7], (const float*)d_in[10]};
    float* out = (float*)d_out;

    char* ws = (char*)d_ws;
    auto carve = [&](size_t bytes) {
        char* p = ws;
        ws += (bytes + 255) & ~(size_t)255;
        return p;
    };
    unsigned short* buf0 = (unsigned short*)carve((size_t)NN * DD * 2);
    unsigned short* buf1 = (unsigned short*)carve((size_t)NN * DD * 2);
    unsigned short* wtall = (unsigned short*)carve((size_t)6 * DD * DD * 2);
    int* gcnt    = (int*)carve((size_t)2 * NBUCK * sizeof(int));  // gcnt + gcursor
    int* gcursor = gcnt + NBUCK;
    int* gbase   = (int*)carve((size_t)(NBUCK + 1) * sizeof(int));
    int* offs    = (int*)carve((size_t)(NN + 1) * sizeof(int));
    uint2* ebuf  = (uint2*)carve((size_t)NE * sizeof(uint2));     // 12.8 MB
    int* csr_col = (int*)carve((size_t)NE * sizeof(int));         // 6.4 MB

    hipMemsetAsync(gcnt, 0, (size_t)2 * NBUCK * sizeof(int), stream);

    prep_kernel<<<CVX_BLK + CVW_BLK + NBLK_PART, 256, 0, stream>>>(
        x, buf0, Wl[0], Wr[0], Wl[1], Wr[1], Wl[2], Wr[2], wtall, row, gcnt);
    bucket_scan<<<1, 512, 0, stream>>>(gcnt, gbase);
    bucket_scatter<<<NBLK_PART, 256, 0, stream>>>(row, col, gbase, gcursor, ebuf);
    csr_build<<<NBUCK, 256, 0, stream>>>(ebuf, gbase, offs, csr_col);

    const int ngrid = (NN + BM - 1) / BM;   // 1563

    unsigned short* hin = buf0;
    unsigned short* hout = buf1;
    for (int lyr = 0; lyr < 3; ++lyr) {
        float* o = out + (size_t)lyr * NN * DD;
        fused_layer<<<ngrid, 256, 0, stream>>>(
            hin, offs, csr_col,
            wtall + (size_t)2 * lyr * DD * DD, wtall + (size_t)(2 * lyr + 1) * DD * DD,
            bb[lyr], o, (lyr < 2) ? hout : (unsigned short*)nullptr);
        unsigned short* t = hin; hin = hout; hout = t;
    }
}